// Round 1
// baseline (428.939 us; speedup 1.0000x reference)
//
#include <hip/hip_runtime.h>
#include <hip/hip_bf16.h>

#define N_ROWS 8192
#define DIM    1024
#define NCLS   10240
#define S_SCALE 30.0f
#define M_LARGE 0.4f
#define M_SMALL 0.1f

typedef __attribute__((ext_vector_type(8))) short bf16x8;
typedef __attribute__((ext_vector_type(4))) float f32x4;

__device__ __forceinline__ unsigned short f2bf(float f){
    unsigned int u = __builtin_bit_cast(unsigned int, f);
    unsigned int r = (u + 0x7fffu + ((u >> 16) & 1u)) >> 16;
    return (unsigned short)r;
}

// ---------------- norms: inverse L2 norm per row of x and w; zero gsum ----------------
__global__ void norms_kernel(const float* __restrict__ x, const float* __restrict__ w,
                             float* __restrict__ inv_x, float* __restrict__ inv_w,
                             float* __restrict__ gsum){
    int b = blockIdx.x;
    const float* base = (b < N_ROWS) ? (x + (size_t)b * DIM)
                                     : (w + (size_t)(b - N_ROWS) * DIM);
    const float4* p4 = (const float4*)base;
    float4 v = p4[threadIdx.x];                       // 256 threads * 4 = 1024
    float ss = v.x*v.x + v.y*v.y + v.z*v.z + v.w*v.w;
    #pragma unroll
    for (int o = 32; o; o >>= 1) ss += __shfl_down(ss, o);
    __shared__ float part[4];
    int lane = threadIdx.x & 63, wid = threadIdx.x >> 6;
    if (lane == 0) part[wid] = ss;
    __syncthreads();
    if (threadIdx.x == 0){
        float t = part[0] + part[1] + part[2] + part[3];
        float inv = 1.0f / fmaxf(sqrtf(t), 1e-12f);
        if (b < N_ROWS){ inv_x[b] = inv; gsum[b] = 0.0f; }
        else            inv_w[b - N_ROWS] = inv;
    }
}

// ---------------- target logit: exact f32 dot x_i . w_label ----------------
__global__ void target_kernel(const float* __restrict__ x, const float* __restrict__ w,
                              const int* __restrict__ labels,
                              const float* __restrict__ inv_x, const float* __restrict__ inv_w,
                              float* __restrict__ tgt){
    int wid = threadIdx.x >> 6, lane = threadIdx.x & 63;
    int i = blockIdx.x * 4 + wid;
    int lab = labels[i];
    const float4* xp = (const float4*)(x + (size_t)i   * DIM);
    const float4* wp = (const float4*)(w + (size_t)lab * DIM);
    float acc = 0.f;
    #pragma unroll
    for (int c = 0; c < 4; ++c){
        float4 a = xp[c*64 + lane];
        float4 b = wp[c*64 + lane];
        acc += a.x*b.x + a.y*b.y + a.z*b.z + a.w*b.w;
    }
    #pragma unroll
    for (int o = 32; o; o >>= 1) acc += __shfl_down(acc, o);
    if (lane == 0){
        float c = acc * inv_x[i] * inv_w[lab];
        c = fminf(fmaxf(c, -1.f), 1.f);
        tgt[i] = c;
    }
}

// ---------------- fused GEMM + exp + row-sum ----------------
// Tile 128x128, BK=64, 256 threads = 4 waves (2x2), each wave 64x64 via 4x4 16x16x32 MFMA frags.
__global__ __launch_bounds__(256) void gemm_kernel(const float* __restrict__ x, const float* __restrict__ w,
                            const float* __restrict__ inv_x, const float* __restrict__ inv_w,
                            float* __restrict__ gsum){
    __shared__ unsigned short As[128*64];
    __shared__ unsigned short Bs[128*64];
    __shared__ float sumrow[128];
    int t = threadIdx.x;
    int row0 = blockIdx.y * 128;
    int col0 = blockIdx.x * 128;
    int wid = t >> 6, lane = t & 63;
    int wm = wid >> 1, wn = wid & 1;
    int g = lane >> 4, l16 = lane & 15;

    f32x4 acc[4][4] = {};
    if (t < 128) sumrow[t] = 0.f;

    for (int k0 = 0; k0 < DIM; k0 += 64){
        __syncthreads();
        #pragma unroll
        for (int s = 0; s < 4; ++s){
            int idx = s*256 + t;
            int r  = idx >> 3;
            int c8 = (idx & 7) << 3;
            int e  = (r<<6) + (c8 ^ ((r&7)<<3));   // XOR-swizzled elem index
            {   // A tile: rows of x, scaled by inv_x
                const float* gp = x + (size_t)(row0 + r)*DIM + k0 + c8;
                float sc = inv_x[row0 + r];
                float4 v0 = *(const float4*)gp;
                float4 v1 = *(const float4*)(gp+4);
                uint4 pk;
                pk.x = f2bf(v0.x*sc) | ((unsigned)f2bf(v0.y*sc) << 16);
                pk.y = f2bf(v0.z*sc) | ((unsigned)f2bf(v0.w*sc) << 16);
                pk.z = f2bf(v1.x*sc) | ((unsigned)f2bf(v1.y*sc) << 16);
                pk.w = f2bf(v1.z*sc) | ((unsigned)f2bf(v1.w*sc) << 16);
                *(uint4*)&As[e] = pk;
            }
            {   // B tile: rows of w, scaled by inv_w
                const float* gp = w + (size_t)(col0 + r)*DIM + k0 + c8;
                float sc = inv_w[col0 + r];
                float4 v0 = *(const float4*)gp;
                float4 v1 = *(const float4*)(gp+4);
                uint4 pk;
                pk.x = f2bf(v0.x*sc) | ((unsigned)f2bf(v0.y*sc) << 16);
                pk.y = f2bf(v0.z*sc) | ((unsigned)f2bf(v0.w*sc) << 16);
                pk.z = f2bf(v1.x*sc) | ((unsigned)f2bf(v1.y*sc) << 16);
                pk.w = f2bf(v1.z*sc) | ((unsigned)f2bf(v1.w*sc) << 16);
                *(uint4*)&Bs[e] = pk;
            }
        }
        __syncthreads();
        #pragma unroll
        for (int kk = 0; kk < 2; ++kk){
            int cofs = kk*32 + g*8;
            bf16x8 af[4], bfr[4];
            #pragma unroll
            for (int m = 0; m < 4; ++m){
                int r = wm*64 + m*16 + l16;
                af[m] = *(bf16x8*)&As[(r<<6) + (cofs ^ ((r&7)<<3))];
            }
            #pragma unroll
            for (int n = 0; n < 4; ++n){
                int r = wn*64 + n*16 + l16;
                bfr[n] = *(bf16x8*)&Bs[(r<<6) + (cofs ^ ((r&7)<<3))];
            }
            #pragma unroll
            for (int m = 0; m < 4; ++m)
                #pragma unroll
                for (int n = 0; n < 4; ++n)
                    acc[m][n] = __builtin_amdgcn_mfma_f32_16x16x32_bf16(af[m], bfr[n], acc[m][n], 0, 0, 0);
        }
    }

    // epilogue: exp(S*clip(.)) and row-sum
    #pragma unroll
    for (int m = 0; m < 4; ++m){
        #pragma unroll
        for (int rg = 0; rg < 4; ++rg){
            int rl = wm*64 + m*16 + g*4 + rg;   // local row of this value
            float v = 0.f;
            #pragma unroll
            for (int n = 0; n < 4; ++n){
                float c = acc[m][n][rg];
                c = fminf(fmaxf(c, -1.f), 1.f);
                v += __expf(S_SCALE * c);
            }
            v += __shfl_xor(v, 1);
            v += __shfl_xor(v, 2);
            v += __shfl_xor(v, 4);
            v += __shfl_xor(v, 8);
            if (l16 == 0) atomicAdd(&sumrow[rl], v);
        }
    }
    __syncthreads();
    if (t < 128) atomicAdd(&gsum[row0 + t], sumrow[t]);
}

// ---------------- finalize: per-row loss, mean ----------------
__global__ void finalize_kernel(const float* __restrict__ tgt, const float* __restrict__ gsum,
                                const int* __restrict__ labels, float* __restrict__ out){
    double local = 0.0;
    for (int i = threadIdx.x; i < N_ROWS; i += 256){
        float tv = tgt[i];
        float m  = (labels[i] <= 5) ? M_LARGE : M_SMALL;
        float numer = S_SCALE * (tv - m);
        float excl  = gsum[i] - __expf(S_SCALE * tv);
        float denom = __expf(numer) + excl;
        float L = numer - logf(denom);
        local += (double)L;
    }
    #pragma unroll
    for (int o = 32; o; o >>= 1) local += __shfl_down(local, o);
    __shared__ double part[4];
    int lane = threadIdx.x & 63, wid = threadIdx.x >> 6;
    if (lane == 0) part[wid] = local;
    __syncthreads();
    if (threadIdx.x == 0){
        double s = part[0] + part[1] + part[2] + part[3];
        out[0] = (float)(-s / (double)N_ROWS);
    }
}

extern "C" void kernel_launch(void* const* d_in, const int* in_sizes, int n_in,
                              void* d_out, int out_size, void* d_ws, size_t ws_size,
                              hipStream_t stream) {
    const float* x      = (const float*)d_in[0];
    const int*   labels = (const int*)  d_in[1];
    const float* w      = (const float*)d_in[2];

    float* ws    = (float*)d_ws;
    float* inv_x = ws;                    // N
    float* inv_w = inv_x + N_ROWS;        // C
    float* tgt   = inv_w + NCLS;          // N
    float* gsum  = tgt   + N_ROWS;        // N

    norms_kernel<<<N_ROWS + NCLS, 256, 0, stream>>>(x, w, inv_x, inv_w, gsum);
    target_kernel<<<N_ROWS/4, 256, 0, stream>>>(x, w, labels, inv_x, inv_w, tgt);
    dim3 grid(NCLS/128, N_ROWS/128);
    gemm_kernel<<<grid, 256, 0, stream>>>(x, w, inv_x, inv_w, gsum);
    finalize_kernel<<<1, 256, 0, stream>>>(tgt, gsum, labels, (float*)d_out);
}

// Round 2
// 288.627 us; speedup vs baseline: 1.4861x; 1.4861x over previous
//
#include <hip/hip_runtime.h>
#include <hip/hip_bf16.h>

#define N_ROWS 8192
#define DIM    1024
#define NCLS   10240
#define S_SCALE 30.0f
#define M_LARGE 0.4f
#define M_SMALL 0.1f

typedef __attribute__((ext_vector_type(8))) short bf16x8;
typedef __attribute__((ext_vector_type(4))) float f32x4;

__device__ __forceinline__ unsigned short f2bf(float f){
    unsigned int u = __builtin_bit_cast(unsigned int, f);
    unsigned int r = (u + 0x7fffu + ((u >> 16) & 1u)) >> 16;
    return (unsigned short)r;
}

#define GLD16(gp, lp) __builtin_amdgcn_global_load_lds( \
    (const __attribute__((address_space(1))) unsigned int*)(gp), \
    (__attribute__((address_space(3))) unsigned int*)(lp), 16, 0, 0)

// ---------------- prep: inv L2 norms + raw f32->bf16 conversion, zero gsum ----------------
__global__ void prep_kernel(const float* __restrict__ x, const float* __restrict__ w,
                            float* __restrict__ inv_x, float* __restrict__ inv_w,
                            float* __restrict__ gsum,
                            unsigned short* __restrict__ xb, unsigned short* __restrict__ wb){
    int b = blockIdx.x;
    bool isx = (b < N_ROWS);
    int r = isx ? b : b - N_ROWS;
    const float4* src = (const float4*)((isx ? x : w) + (size_t)r * DIM);
    float4 v = src[threadIdx.x];                      // 256 threads * 4 = 1024
    ushort4 pk;
    pk.x = f2bf(v.x); pk.y = f2bf(v.y); pk.z = f2bf(v.z); pk.w = f2bf(v.w);
    ushort4* dst = (ushort4*)((isx ? xb : wb) + (size_t)r * DIM);
    dst[threadIdx.x] = pk;
    float ss = v.x*v.x + v.y*v.y + v.z*v.z + v.w*v.w;
    #pragma unroll
    for (int o = 32; o; o >>= 1) ss += __shfl_down(ss, o);
    __shared__ float part[4];
    int lane = threadIdx.x & 63, wid = threadIdx.x >> 6;
    if (lane == 0) part[wid] = ss;
    __syncthreads();
    if (threadIdx.x == 0){
        float t = part[0] + part[1] + part[2] + part[3];
        float inv = 1.0f / fmaxf(sqrtf(t), 1e-12f);
        if (isx){ inv_x[r] = inv; gsum[r] = 0.0f; }
        else      inv_w[r] = inv;
    }
}

// ---------------- target logit: exact f32 dot x_i . w_label ----------------
__global__ void target_kernel(const float* __restrict__ x, const float* __restrict__ w,
                              const int* __restrict__ labels,
                              const float* __restrict__ inv_x, const float* __restrict__ inv_w,
                              float* __restrict__ tgt){
    int wid = threadIdx.x >> 6, lane = threadIdx.x & 63;
    int i = blockIdx.x * 4 + wid;
    int lab = labels[i];
    const float4* xp = (const float4*)(x + (size_t)i   * DIM);
    const float4* wp = (const float4*)(w + (size_t)lab * DIM);
    float acc = 0.f;
    #pragma unroll
    for (int c = 0; c < 4; ++c){
        float4 a = xp[c*64 + lane];
        float4 b = wp[c*64 + lane];
        acc += a.x*b.x + a.y*b.y + a.z*b.z + a.w*b.w;
    }
    #pragma unroll
    for (int o = 32; o; o >>= 1) acc += __shfl_down(acc, o);
    if (lane == 0){
        float c = acc * inv_x[i] * inv_w[lab];
        c = fminf(fmaxf(c, -1.f), 1.f);
        tgt[i] = c;
    }
}

// ---------------- fused bf16 GEMM + scale + exp + row-sum ----------------
// m97 structure: 128x128 tile, BK=64, 4 waves (2x2), global_load_lds(16B) with
// pre-swizzled source, swizzled ds_read_b128 fragment reads (conflict-free).
#define NWG ((N_ROWS/128)*(NCLS/128))   // 64*80 = 5120
__global__ __launch_bounds__(256) void gemm_kernel(
        const unsigned short* __restrict__ xb, const unsigned short* __restrict__ wb,
        const float* __restrict__ inv_x, const float* __restrict__ inv_w,
        float* __restrict__ gsum){
    __shared__ __align__(16) unsigned short As[128*64];
    __shared__ __align__(16) unsigned short Bs[128*64];
    __shared__ float sumrow[128];
    int t = threadIdx.x;
    // bijective XCD swizzle (NWG % 8 == 0): each XCD gets contiguous row-panels
    int bid = blockIdx.x;
    int swz = (bid & 7) * (NWG/8) + (bid >> 3);
    int by = swz / (NCLS/128), bx = swz % (NCLS/128);
    int row0 = by * 128, col0 = bx * 128;
    int wid = t >> 6, lane = t & 63;
    int wm = wid >> 1, wn = wid & 1;
    int g = lane >> 4, l16 = lane & 15;

    f32x4 acc[4][4] = {};
    if (t < 128) sumrow[t] = 0.f;

    // staging addresses: instruction s stages rows [wid*32+s*8, +8), lane -> (row lane>>3, chunk lane&7)
    // LDS dest is linear; global source chunk is pre-swizzled: csrc = (lane&7) ^ ((lane>>3)&7)
    int r_lane = lane >> 3;
    int csrc   = (lane & 7) ^ r_lane;
    const unsigned short* ga = xb + (size_t)(row0 + wid*32 + r_lane) * DIM + csrc * 8;
    const unsigned short* gb = wb + (size_t)(col0 + wid*32 + r_lane) * DIM + csrc * 8;

    for (int k0 = 0; k0 < DIM; k0 += 64){
        __syncthreads();
        #pragma unroll
        for (int s = 0; s < 4; ++s){
            GLD16(ga + (size_t)s*8*DIM + k0, &As[(wid*32 + s*8) * 64]);
            GLD16(gb + (size_t)s*8*DIM + k0, &Bs[(wid*32 + s*8) * 64]);
        }
        __syncthreads();   // compiler emits s_waitcnt vmcnt(0) before s_barrier
        #pragma unroll
        for (int kk = 0; kk < 2; ++kk){
            int ck = kk*4 + g;            // logical 16B chunk within the 128B row
            bf16x8 af[4], bfr[4];
            #pragma unroll
            for (int m = 0; m < 4; ++m){
                int r = wm*64 + m*16 + l16;
                af[m] = *(bf16x8*)&As[r*64 + ((ck ^ (r & 7)) << 3)];
            }
            #pragma unroll
            for (int n = 0; n < 4; ++n){
                int r = wn*64 + n*16 + l16;
                bfr[n] = *(bf16x8*)&Bs[r*64 + ((ck ^ (r & 7)) << 3)];
            }
            #pragma unroll
            for (int m = 0; m < 4; ++m)
                #pragma unroll
                for (int n = 0; n < 4; ++n)
                    acc[m][n] = __builtin_amdgcn_mfma_f32_16x16x32_bf16(af[m], bfr[n], acc[m][n], 0, 0, 0);
        }
    }

    // epilogue: scale by inv_x[i]*inv_w[j], clamp, exp(S*.), row-sum
    float iw[4];
    #pragma unroll
    for (int n = 0; n < 4; ++n) iw[n] = inv_w[col0 + wn*64 + n*16 + l16];
    #pragma unroll
    for (int m = 0; m < 4; ++m){
        #pragma unroll
        for (int rg = 0; rg < 4; ++rg){
            int rl = wm*64 + m*16 + g*4 + rg;        // local row of this value
            float ix = inv_x[row0 + rl];
            float v = 0.f;
            #pragma unroll
            for (int n = 0; n < 4; ++n){
                float c = acc[m][n][rg] * ix * iw[n];
                c = fminf(fmaxf(c, -1.f), 1.f);
                v += __expf(S_SCALE * c);
            }
            v += __shfl_xor(v, 1);
            v += __shfl_xor(v, 2);
            v += __shfl_xor(v, 4);
            v += __shfl_xor(v, 8);
            if (l16 == 0) atomicAdd(&sumrow[rl], v);
        }
    }
    __syncthreads();
    if (t < 128) atomicAdd(&gsum[row0 + t], sumrow[t]);
}

// ---------------- finalize: per-row loss, mean ----------------
__global__ void finalize_kernel(const float* __restrict__ tgt, const float* __restrict__ gsum,
                                const int* __restrict__ labels, float* __restrict__ out){
    double local = 0.0;
    for (int i = threadIdx.x; i < N_ROWS; i += 256){
        float tv = tgt[i];
        float m  = (labels[i] <= 5) ? M_LARGE : M_SMALL;
        float numer = S_SCALE * (tv - m);
        float excl  = gsum[i] - __expf(S_SCALE * tv);
        float denom = __expf(numer) + excl;
        float L = numer - logf(denom);
        local += (double)L;
    }
    #pragma unroll
    for (int o = 32; o; o >>= 1) local += __shfl_down(local, o);
    __shared__ double part[4];
    int lane = threadIdx.x & 63, wid = threadIdx.x >> 6;
    if (lane == 0) part[wid] = local;
    __syncthreads();
    if (threadIdx.x == 0){
        double s = part[0] + part[1] + part[2] + part[3];
        out[0] = (float)(-s / (double)N_ROWS);
    }
}

extern "C" void kernel_launch(void* const* d_in, const int* in_sizes, int n_in,
                              void* d_out, int out_size, void* d_ws, size_t ws_size,
                              hipStream_t stream) {
    const float* x      = (const float*)d_in[0];
    const int*   labels = (const int*)  d_in[1];
    const float* w      = (const float*)d_in[2];

    float* ws    = (float*)d_ws;
    float* inv_x = ws;                    // N
    float* inv_w = inv_x + N_ROWS;        // C
    float* tgt   = inv_w + NCLS;          // N
    float* gsum  = tgt   + N_ROWS;        // N
    unsigned short* xb = (unsigned short*)(gsum + N_ROWS);  // N*D bf16
    unsigned short* wb = xb + (size_t)N_ROWS * DIM;         // C*D bf16

    prep_kernel<<<N_ROWS + NCLS, 256, 0, stream>>>(x, w, inv_x, inv_w, gsum, xb, wb);
    target_kernel<<<N_ROWS/4, 256, 0, stream>>>(x, w, labels, inv_x, inv_w, tgt);
    gemm_kernel<<<NWG, 256, 0, stream>>>(xb, wb, inv_x, inv_w, gsum);
    finalize_kernel<<<1, 256, 0, stream>>>(tgt, gsum, labels, (float*)d_out);
}

// Round 4
// 229.147 us; speedup vs baseline: 1.8719x; 1.2596x over previous
//
#include <hip/hip_runtime.h>
#include <hip/hip_bf16.h>

#define N_ROWS 8192
#define DIM    1024
#define NCLS   10240
#define S_SCALE 30.0f
#define M_LARGE 0.4f
#define M_SMALL 0.1f

typedef __attribute__((ext_vector_type(8))) short bf16x8;
typedef __attribute__((ext_vector_type(4))) float f32x4;

__device__ __forceinline__ unsigned short f2bf(float f){
    unsigned int u = __builtin_bit_cast(unsigned int, f);
    unsigned int r = (u + 0x7fffu + ((u >> 16) & 1u)) >> 16;
    return (unsigned short)r;
}

#define GLD16(gp, lp) __builtin_amdgcn_global_load_lds( \
    (const __attribute__((address_space(1))) unsigned int*)(gp), \
    (__attribute__((address_space(3))) unsigned int*)(lp), 16, 0, 0)

// ---------------- prep: inv L2 norms + raw f32->bf16 conversion, zero gsum ----------------
__global__ void prep_kernel(const float* __restrict__ x, const float* __restrict__ w,
                            float* __restrict__ inv_x, float* __restrict__ inv_w,
                            float* __restrict__ gsum,
                            unsigned short* __restrict__ xb, unsigned short* __restrict__ wb){
    int b = blockIdx.x;
    bool isx = (b < N_ROWS);
    int r = isx ? b : b - N_ROWS;
    const float4* src = (const float4*)((isx ? x : w) + (size_t)r * DIM);
    float4 v = src[threadIdx.x];                      // 256 threads * 4 = 1024
    ushort4 pk;
    pk.x = f2bf(v.x); pk.y = f2bf(v.y); pk.z = f2bf(v.z); pk.w = f2bf(v.w);
    ushort4* dst = (ushort4*)((isx ? xb : wb) + (size_t)r * DIM);
    dst[threadIdx.x] = pk;
    float ss = v.x*v.x + v.y*v.y + v.z*v.z + v.w*v.w;
    #pragma unroll
    for (int o = 32; o; o >>= 1) ss += __shfl_down(ss, o);
    __shared__ float part[4];
    int lane = threadIdx.x & 63, wid = threadIdx.x >> 6;
    if (lane == 0) part[wid] = ss;
    __syncthreads();
    if (threadIdx.x == 0){
        float t = part[0] + part[1] + part[2] + part[3];
        float inv = 1.0f / fmaxf(sqrtf(t), 1e-12f);
        if (isx){ inv_x[r] = inv; gsum[r] = 0.0f; }
        else      inv_w[r] = inv;
    }
}

// ---------------- target logit: exact f32 dot x_i . w_label ----------------
__global__ void target_kernel(const float* __restrict__ x, const float* __restrict__ w,
                              const int* __restrict__ labels,
                              const float* __restrict__ inv_x, const float* __restrict__ inv_w,
                              float* __restrict__ tgt){
    int wid = threadIdx.x >> 6, lane = threadIdx.x & 63;
    int i = blockIdx.x * 4 + wid;
    int lab = labels[i];
    const float4* xp = (const float4*)(x + (size_t)i   * DIM);
    const float4* wp = (const float4*)(w + (size_t)lab * DIM);
    float acc = 0.f;
    #pragma unroll
    for (int c = 0; c < 4; ++c){
        float4 a = xp[c*64 + lane];
        float4 b = wp[c*64 + lane];
        acc += a.x*b.x + a.y*b.y + a.z*b.z + a.w*b.w;
    }
    #pragma unroll
    for (int o = 32; o; o >>= 1) acc += __shfl_down(acc, o);
    if (lane == 0){
        float c = acc * inv_x[i] * inv_w[lab];
        c = fminf(fmaxf(c, -1.f), 1.f);
        tgt[i] = c;
    }
}

// ---------------- fused bf16 GEMM (256x256 tile, 4-phase/K-tile pipeline) ----------------
#define BM 256
#define BN 256
#define BK 64
#define NTILE (DIM/BK)       // 16
#define GRID_X (NCLS/BN)     // 40
#define GRID_Y (N_ROWS/BM)   // 32
#define NWG (GRID_X*GRID_Y)  // 1280, % 8 == 0

__global__ __launch_bounds__(512, 2) void gemm_kernel(
        const unsigned short* __restrict__ xb, const unsigned short* __restrict__ wb,
        const float* __restrict__ inv_x, const float* __restrict__ inv_w,
        float* __restrict__ gsum){
    __shared__ __align__(16) unsigned short As[2][BM*BK];   // 2 x 32 KB
    __shared__ __align__(16) unsigned short Bs[2][BN*BK];   // 2 x 32 KB
    __shared__ float sumrow[BM];

    int tid = threadIdx.x;
    int bid = blockIdx.x;
    // bijective XCD swizzle
    int swz = (bid & 7) * (NWG/8) + (bid >> 3);
    int by = swz / GRID_X, bx = swz % GRID_X;
    int row0 = by * BM, col0 = bx * BN;
    int wid = tid >> 6, lane = tid & 63;
    int wm = wid >> 2, wn = wid & 3;           // 2M x 4N wave grid; wave owns 128x64
    int g = lane >> 4, l16 = lane & 15;

    if (tid < BM) sumrow[tid] = 0.f;

    // staging geometry: one GLD16 instr = 512 thr x 16B = 64 rows x 64 cols
    int srow = tid >> 3;                       // 0..63
    int csrc = (tid & 7) ^ (srow & 7);         // pre-swizzled source chunk
    const unsigned short* gA = xb + (size_t)(row0 + srow) * DIM + csrc * 8;
    const unsigned short* gB = wb + (size_t)(col0 + srow) * DIM + csrc * 8;
    int ldso = srow * BK + (tid & 7) * 8;      // linear LDS dest (elements)

    f32x4 acc[8][4] = {};

    // prologue: stage tile 0 fully
    #pragma unroll
    for (int h = 0; h < 4; ++h){
        GLD16(gA + (size_t)(h*64)*DIM, &As[0][h*64*BK + ldso]);
        GLD16(gB + (size_t)(h*64)*DIM, &Bs[0][h*64*BK + ldso]);
    }
    asm volatile("s_waitcnt vmcnt(0)" ::: "memory");
    __builtin_amdgcn_s_barrier();

    for (int kt = 0; kt < NTILE; ++kt){
        int b = kt & 1, nb = b ^ 1;
        int knext = (kt + 1) * BK;
        bool pre = (kt + 1 < NTILE);
        bf16x8 af[4], bfv[4];

        // ---- P0: read A m0-3 k0 + B n0-3 k0 ; stage next A rows 0-127
        #pragma unroll
        for (int m = 0; m < 4; ++m){
            int r = wm*128 + m*16 + l16;
            af[m] = *(const bf16x8*)&As[b][r*BK + ((g ^ (r & 7)) << 3)];
        }
        #pragma unroll
        for (int n = 0; n < 4; ++n){
            int r = wn*64 + n*16 + l16;
            bfv[n] = *(const bf16x8*)&Bs[b][r*BK + ((g ^ (r & 7)) << 3)];
        }
        if (pre){
            GLD16(gA + knext,                    &As[nb][ldso]);
            GLD16(gA + knext + (size_t)64*DIM,   &As[nb][64*BK + ldso]);
        }
        __builtin_amdgcn_s_barrier();
        asm volatile("s_waitcnt lgkmcnt(0)" ::: "memory");
        __builtin_amdgcn_sched_barrier(0);
        __builtin_amdgcn_s_setprio(1);
        #pragma unroll
        for (int m = 0; m < 4; ++m)
            #pragma unroll
            for (int n = 0; n < 4; ++n)
                acc[m][n] = __builtin_amdgcn_mfma_f32_16x16x32_bf16(af[m], bfv[n], acc[m][n], 0, 0, 0);
        __builtin_amdgcn_s_setprio(0);
        __builtin_amdgcn_s_barrier();

        // ---- P1: read A m4-7 k0 ; stage next A rows 128-255 ; reuse B k0 regs
        #pragma unroll
        for (int m = 0; m < 4; ++m){
            int r = wm*128 + (m+4)*16 + l16;
            af[m] = *(const bf16x8*)&As[b][r*BK + ((g ^ (r & 7)) << 3)];
        }
        if (pre){
            GLD16(gA + knext + (size_t)128*DIM,  &As[nb][128*BK + ldso]);
            GLD16(gA + knext + (size_t)192*DIM,  &As[nb][192*BK + ldso]);
        }
        __builtin_amdgcn_s_barrier();
        asm volatile("s_waitcnt lgkmcnt(0)" ::: "memory");
        __builtin_amdgcn_sched_barrier(0);
        __builtin_amdgcn_s_setprio(1);
        #pragma unroll
        for (int m = 0; m < 4; ++m)
            #pragma unroll
            for (int n = 0; n < 4; ++n)
                acc[m+4][n] = __builtin_amdgcn_mfma_f32_16x16x32_bf16(af[m], bfv[n], acc[m+4][n], 0, 0, 0);
        __builtin_amdgcn_s_setprio(0);
        __builtin_amdgcn_s_barrier();

        // ---- P2: read A m0-3 k1 + B n0-3 k1 ; stage next B rows 0-127
        #pragma unroll
        for (int m = 0; m < 4; ++m){
            int r = wm*128 + m*16 + l16;
            af[m] = *(const bf16x8*)&As[b][r*BK + (((4+g) ^ (r & 7)) << 3)];
        }
        #pragma unroll
        for (int n = 0; n < 4; ++n){
            int r = wn*64 + n*16 + l16;
            bfv[n] = *(const bf16x8*)&Bs[b][r*BK + (((4+g) ^ (r & 7)) << 3)];
        }
        if (pre){
            GLD16(gB + knext,                    &Bs[nb][ldso]);
            GLD16(gB + knext + (size_t)64*DIM,   &Bs[nb][64*BK + ldso]);
        }
        __builtin_amdgcn_s_barrier();
        asm volatile("s_waitcnt lgkmcnt(0)" ::: "memory");
        __builtin_amdgcn_sched_barrier(0);
        __builtin_amdgcn_s_setprio(1);
        #pragma unroll
        for (int m = 0; m < 4; ++m)
            #pragma unroll
            for (int n = 0; n < 4; ++n)
                acc[m][n] = __builtin_amdgcn_mfma_f32_16x16x32_bf16(af[m], bfv[n], acc[m][n], 0, 0, 0);
        __builtin_amdgcn_s_setprio(0);
        __builtin_amdgcn_s_barrier();

        // ---- P3: read A m4-7 k1 ; stage next B rows 128-255
        #pragma unroll
        for (int m = 0; m < 4; ++m){
            int r = wm*128 + (m+4)*16 + l16;
            af[m] = *(const bf16x8*)&As[b][r*BK + (((4+g) ^ (r & 7)) << 3)];
        }
        if (pre){
            GLD16(gB + knext + (size_t)128*DIM,  &Bs[nb][128*BK + ldso]);
            GLD16(gB + knext + (size_t)192*DIM,  &Bs[nb][192*BK + ldso]);
        }
        __builtin_amdgcn_s_barrier();
        asm volatile("s_waitcnt lgkmcnt(0)" ::: "memory");
        __builtin_amdgcn_sched_barrier(0);
        __builtin_amdgcn_s_setprio(1);
        #pragma unroll
        for (int m = 0; m < 4; ++m)
            #pragma unroll
            for (int n = 0; n < 4; ++n)
                acc[m+4][n] = __builtin_amdgcn_mfma_f32_16x16x32_bf16(af[m], bfv[n], acc[m+4][n], 0, 0, 0);
        __builtin_amdgcn_s_setprio(0);

        // ---- K-tile boundary: all of next tile's stages are 1-4 phases old
        asm volatile("s_waitcnt vmcnt(0)" ::: "memory");
        __builtin_amdgcn_sched_barrier(0);
        __builtin_amdgcn_s_barrier();
    }

    // epilogue: scale by inv_x[i]*inv_w[j], clamp, exp(S*.), row-sum
    float iw[4];
    #pragma unroll
    for (int n = 0; n < 4; ++n) iw[n] = inv_w[col0 + wn*64 + n*16 + l16];
    #pragma unroll
    for (int m = 0; m < 8; ++m){
        #pragma unroll
        for (int rg = 0; rg < 4; ++rg){
            int rl = wm*128 + m*16 + g*4 + rg;       // local row of this value
            float ix = inv_x[row0 + rl];
            float v = 0.f;
            #pragma unroll
            for (int n = 0; n < 4; ++n){
                float c = acc[m][n][rg] * ix * iw[n];
                c = fminf(fmaxf(c, -1.f), 1.f);
                v += __expf(S_SCALE * c);
            }
            v += __shfl_xor(v, 1);
            v += __shfl_xor(v, 2);
            v += __shfl_xor(v, 4);
            v += __shfl_xor(v, 8);
            if (l16 == 0) atomicAdd(&sumrow[rl], v);
        }
    }
    __syncthreads();
    if (tid < BM) atomicAdd(&gsum[row0 + tid], sumrow[tid]);
}

// ---------------- finalize: per-row loss, mean ----------------
__global__ void finalize_kernel(const float* __restrict__ tgt, const float* __restrict__ gsum,
                                const int* __restrict__ labels, float* __restrict__ out){
    double local = 0.0;
    for (int i = threadIdx.x; i < N_ROWS; i += 256){
        float tv = tgt[i];
        float m  = (labels[i] <= 5) ? M_LARGE : M_SMALL;
        float numer = S_SCALE * (tv - m);
        float excl  = gsum[i] - __expf(S_SCALE * tv);
        float denom = __expf(numer) + excl;
        float L = numer - logf(denom);
        local += (double)L;
    }
    #pragma unroll
    for (int o = 32; o; o >>= 1) local += __shfl_down(local, o);
    __shared__ double part[4];
    int lane = threadIdx.x & 63, wid = threadIdx.x >> 6;
    if (lane == 0) part[wid] = local;
    __syncthreads();
    if (threadIdx.x == 0){
        double s = part[0] + part[1] + part[2] + part[3];
        out[0] = (float)(-s / (double)N_ROWS);
    }
}

extern "C" void kernel_launch(void* const* d_in, const int* in_sizes, int n_in,
                              void* d_out, int out_size, void* d_ws, size_t ws_size,
                              hipStream_t stream) {
    const float* x      = (const float*)d_in[0];
    const int*   labels = (const int*)  d_in[1];
    const float* w      = (const float*)d_in[2];

    float* ws    = (float*)d_ws;
    float* inv_x = ws;                    // N
    float* inv_w = inv_x + N_ROWS;        // C
    float* tgt   = inv_w + NCLS;          // N
    float* gsum  = tgt   + N_ROWS;        // N
    unsigned short* xb = (unsigned short*)(gsum + N_ROWS);  // N*D bf16
    unsigned short* wb = xb + (size_t)N_ROWS * DIM;         // C*D bf16

    prep_kernel<<<N_ROWS + NCLS, 256, 0, stream>>>(x, w, inv_x, inv_w, gsum, xb, wb);
    target_kernel<<<N_ROWS/4, 256, 0, stream>>>(x, w, labels, inv_x, inv_w, tgt);
    gemm_kernel<<<NWG, 512, 0, stream>>>(xb, wb, inv_x, inv_w, gsum);
    finalize_kernel<<<1, 256, 0, stream>>>(tgt, gsum, labels, (float*)d_out);
}